// Round 1
// baseline (196.610 us; speedup 1.0000x reference)
//
#include <hip/hip_runtime.h>

#define N_SAMPLES 8192
#define BLOCK 256
// elements per thread = 8192/256 = 32 -> 8 float4 loads

__global__ __launch_bounds__(BLOCK) void noise_layer_kernel(
    const float* __restrict__ pub_sign,   // (batch,)
    const float* __restrict__ priv_sign,  // (batch, n_samples)
    const float* __restrict__ param_b,    // (1,1)
    const float* __restrict__ param_c,    // (1,1)
    float* __restrict__ out)              // (batch,)
{
    const int b = blockIdx.x;
    const float B = param_b[0];
    const float C = param_c[0];
    const float base = pub_sign[b] * B;   // pub * B, broadcast over samples

    const float4* row = reinterpret_cast<const float4*>(
        priv_sign + (size_t)b * N_SAMPLES);

    float sum = 0.0f;
#pragma unroll
    for (int i = 0; i < N_SAMPLES / (BLOCK * 4); ++i) {
        float4 v = row[threadIdx.x + i * BLOCK];
#pragma unroll
        for (int j = 0; j < 4; ++j) {
            float p = (j == 0) ? v.x : (j == 1) ? v.y : (j == 2) ? v.z : v.w;
            float s = fmaf(p, C, base);
            s = fminf(20.0f, fmaxf(-20.0f, s));
            // 2*sigmoid(s) - 1 == (1 - e^{-s}) / (1 + e^{-s})
            float e = __expf(-s);
            sum += (1.0f - e) / (1.0f + e);
        }
    }

    // wave (64-lane) shuffle reduction
#pragma unroll
    for (int off = 32; off > 0; off >>= 1)
        sum += __shfl_down(sum, off, 64);

    __shared__ float part[BLOCK / 64];
    const int wave = threadIdx.x >> 6;
    const int lane = threadIdx.x & 63;
    if (lane == 0) part[wave] = sum;
    __syncthreads();

    if (threadIdx.x == 0) {
        float t = 0.0f;
#pragma unroll
        for (int w = 0; w < BLOCK / 64; ++w) t += part[w];
        out[b] = t * (1.0f / (float)N_SAMPLES);
    }
}

extern "C" void kernel_launch(void* const* d_in, const int* in_sizes, int n_in,
                              void* d_out, int out_size, void* d_ws, size_t ws_size,
                              hipStream_t stream) {
    const float* pub_sign  = (const float*)d_in[0];   // (4096,)
    const float* priv_sign = (const float*)d_in[1];   // (4096, 8192, 1)
    const float* param_b   = (const float*)d_in[2];   // (1,1)
    const float* param_c   = (const float*)d_in[3];   // (1,1)
    float* out = (float*)d_out;                       // (4096, 1, 1)

    const int batch = in_sizes[0];                    // 4096
    noise_layer_kernel<<<batch, BLOCK, 0, stream>>>(
        pub_sign, priv_sign, param_b, param_c, out);
}

// Round 2
// 183.856 us; speedup vs baseline: 1.0694x; 1.0694x over previous
//
#include <hip/hip_runtime.h>

#define N_SAMPLES 8192
#define BLOCK 256
// elements per thread = 8192/256 = 32 -> 8 float4 loads

typedef float f32x4 __attribute__((ext_vector_type(4)));

__global__ __launch_bounds__(BLOCK) void noise_layer_kernel(
    const float* __restrict__ pub_sign,   // (batch,)
    const float* __restrict__ priv_sign,  // (batch, n_samples)
    const float* __restrict__ param_b,    // (1,1)
    const float* __restrict__ param_c,    // (1,1)
    float* __restrict__ out)              // (batch,)
{
    const int b = blockIdx.x;
    const float B = param_b[0];
    const float C = param_c[0];
    const float base = pub_sign[b] * B;   // pub * B, broadcast over samples

    const f32x4* row = reinterpret_cast<const f32x4*>(
        priv_sign + (size_t)b * N_SAMPLES);

    float sum = 0.0f;
#pragma unroll
    for (int i = 0; i < N_SAMPLES / (BLOCK * 4); ++i) {
        f32x4 v = __builtin_nontemporal_load(&row[threadIdx.x + i * BLOCK]);
#pragma unroll
        for (int j = 0; j < 4; ++j) {
            float p = v[j];
            float s = fmaf(p, C, base);
            s = fminf(20.0f, fmaxf(-20.0f, s));   // -> v_med3_f32
            // 2*sigmoid(s) - 1 == (1 - e^{-s}) / (1 + e^{-s}), fast rcp (<=1 ulp)
            float e = __expf(-s);
            sum += (1.0f - e) * __builtin_amdgcn_rcpf(1.0f + e);
        }
    }

    // wave (64-lane) shuffle reduction
#pragma unroll
    for (int off = 32; off > 0; off >>= 1)
        sum += __shfl_down(sum, off, 64);

    __shared__ float part[BLOCK / 64];
    const int wave = threadIdx.x >> 6;
    const int lane = threadIdx.x & 63;
    if (lane == 0) part[wave] = sum;
    __syncthreads();

    if (threadIdx.x == 0) {
        float t = 0.0f;
#pragma unroll
        for (int w = 0; w < BLOCK / 64; ++w) t += part[w];
        out[b] = t * (1.0f / (float)N_SAMPLES);
    }
}

extern "C" void kernel_launch(void* const* d_in, const int* in_sizes, int n_in,
                              void* d_out, int out_size, void* d_ws, size_t ws_size,
                              hipStream_t stream) {
    const float* pub_sign  = (const float*)d_in[0];   // (4096,)
    const float* priv_sign = (const float*)d_in[1];   // (4096, 8192, 1)
    const float* param_b   = (const float*)d_in[2];   // (1,1)
    const float* param_c   = (const float*)d_in[3];   // (1,1)
    float* out = (float*)d_out;                       // (4096, 1, 1)

    const int batch = in_sizes[0];                    // 4096
    noise_layer_kernel<<<batch, BLOCK, 0, stream>>>(
        pub_sign, priv_sign, param_b, param_c, out);
}